// Round 6
// baseline (1683.333 us; speedup 1.0000x reference)
//
#include <hip/hip_runtime.h>
#include <hip/hip_bf16.h>

typedef __bf16 bf16_t;
typedef __attribute__((ext_vector_type(8))) __bf16 bf16x8;
typedef __attribute__((ext_vector_type(4))) float f32x4;

// Direct HBM->LDS DMA, 16B per lane. LDS dest = wave-uniform base + lane*16.
#define GLOAD_LDS16(gp, lp)                                                    \
  __builtin_amdgcn_global_load_lds(                                            \
      (const __attribute__((address_space(1))) void*)(gp),                     \
      (__attribute__((address_space(3))) void*)(lp), 16, 0, 0)

// ---------------- prep kernels (tiny) ----------------
__global__ void prep_wvp(const float* __restrict__ Wv, const float* __restrict__ Wp,
                         const float* __restrict__ bp, const float* __restrict__ bv,
                         float* __restrict__ Wvp, float* __restrict__ bvp) {
  const int i = blockIdx.x;
  const int j = threadIdx.x;
  float a = 0.f;
  for (int d = 0; d < 512; ++d) a += Wv[i * 512 + d] * Wp[d * 256 + j];
  Wvp[i * 256 + j] = a;
  if (j == 0) {
    float b = 0.f;
    for (int d = 0; d < 512; ++d) b += Wv[i * 512 + d] * bp[d];
    bvp[i] = b + bv[i];
  }
}

__global__ void prep_wc(const float* __restrict__ Wo, const float* __restrict__ bo,
                        const float* __restrict__ Wvp, const float* __restrict__ bvp,
                        bf16_t* __restrict__ Wc, float* __restrict__ bcomb) {
  const int o = blockIdx.x;
  const int j = threadIdx.x;
  float a = 0.f;
  for (int i = 0; i < 512; ++i) a += Wo[o * 512 + i] * Wvp[i * 256 + j];
  Wc[o * 256 + j] = (bf16_t)a;
  if (j == 0) {
    float b = 0.f;
    for (int i = 0; i < 512; ++i) b += Wo[o * 512 + i] * bvp[i];
    bcomb[o] = b + bo[o];
  }
}

// cast W1 (524288) then W2 (524288) to bf16 (row-major, same layout as source)
__global__ void prep_cast(const float* __restrict__ W1, const float* __restrict__ W2,
                          bf16_t* __restrict__ W1b, bf16_t* __restrict__ W2b) {
  const int idx = (blockIdx.x * 256 + threadIdx.x) * 8;
  const float* s;
  bf16_t* d;
  if (idx < 524288) { s = W1 + idx; d = W1b + idx; }
  else { s = W2 + (idx - 524288); d = W2b + (idx - 524288); }
  float4 u0 = *(const float4*)s;
  float4 u1 = *(const float4*)(s + 4);
  bf16x8 v;
  v[0] = (bf16_t)u0.x; v[1] = (bf16_t)u0.y; v[2] = (bf16_t)u0.z; v[3] = (bf16_t)u0.w;
  v[4] = (bf16_t)u1.x; v[5] = (bf16_t)u1.y; v[6] = (bf16_t)u1.z; v[7] = (bf16_t)u1.w;
  *(bf16x8*)d = v;
}

// ---------------- fused GEMM body ----------------
// C[m][n] = sum_k A[m][k] * Bw[n][k]  (Bw row-major N x K, i.e. X @ W.T)
//
// NEW GEOMETRY (round 6): tile 256 rows x 512 cols, BK=32, 512 threads = 8 waves,
// wave grid 2 row x 4 col, wave-tile 128x128 (acc 8x8 f32x4 = 256 VGPR, 1 wave/SIMD).
// Rationale: previous 64x512 tile staged 36KB per 310 MFMA-cyc/CU = 4.2x over the
// ~56B/cyc/CU L2 supply -> hard ~24% MfmaUtil ceiling (explains rounds 0-5 all
// landing 185-250us). 256x512 halves->quarters staged-bytes/FLOP: 48KB per
// 620 MFMA-cyc/CU = 77B/cyc, at supply.
//
// LDS: 16-row windows of 1 KiB; 16B slot s = r*4 + (q ^ ((r>>1)&3)); staged by
// global_load_lds with pre-swizzled per-lane source (verified: 0 bank conflicts).
// A: 16 windows x 2 bufs (32KB); B: 32 windows x 2 bufs (64KB); LN scratch 8KB.
//
// K-loop (EPI!=0): counted-vmcnt pipeline, 6 DMAs/wave/step:
//   stage(next) -> vmcnt(6) [current done, next in flight] -> barrier ->
//   compute -> barrier.
// EPI 0 keeps __syncthreads loop (fp32 A reg-convert path mixes loads+ds_write).
//
// EPI 0: + bias + cell residual, LayerNorm(g,b) -> bf16 out (stride 512)
// EPI 1: + bias, exact GELU -> bf16 out (stride 1024)
// EPI 2: + bias + bf16 x residual, LayerNorm -> fp32 out (stride 512)
template <int K, int EPI>
__device__ __forceinline__ void gemm_body(
    const float* __restrict__ Af32, const bf16_t* __restrict__ Abf, const int lda,
    const bf16_t* __restrict__ Bw,
    const float* __restrict__ bias,
    const float* __restrict__ cellRes,
    const bf16_t* __restrict__ xRes,
    const float* __restrict__ gamma, const float* __restrict__ beta,
    bf16_t* __restrict__ outBf, float* __restrict__ outF32) {

  __shared__ __align__(16) bf16_t lA[2 * 256 * 32];   // 32 KiB (2 bufs x 16 windows)
  __shared__ __align__(16) bf16_t lB[2 * 512 * 32];   // 64 KiB (2 bufs x 32 windows)
  __shared__ float rs[4][256];
  __shared__ float rss[4][256];

  constexpr int S = K / 32;
  const int t = threadIdx.x;
  const int m0 = blockIdx.x * 256;
  const int n0 = blockIdx.y * 512;  // only nonzero for EPI==1 (N=1024)
  const int lane = t & 63;
  const int w = t >> 6;       // wave 0..7
  const int wr = w >> 2;      // row half 0..1 (128 rows each)
  const int wc = w & 3;       // col quarter 0..3 (128 cols each)
  const int r = lane & 15;
  const int q = lane >> 4;
  const int qs = q ^ ((r >> 1) & 3);

  const int fRd = r * 32 + qs * 8;  // within-window fragment read base

  // staging source mapping: lane l -> (row_in_window = l>>2, chunk = (l&3)^((l>>3)&3))
  const int srow = lane >> 2;
  const int sq = (lane & 3) ^ ((lane >> 3) & 3);

  f32x4 acc[8][8];
#pragma unroll
  for (int i = 0; i < 8; ++i)
#pragma unroll
    for (int j = 0; j < 8; ++j)
#pragma unroll
      for (int p = 0; p < 4; ++p) acc[i][j][p] = 0.f;

  // EPI 0 A-staging: 1024 slots (256 rows x 4 chunks); thread t does slots t, t+512.
  int aWr0 = 0, aWr1 = 0;
  if constexpr (EPI == 0) {
    auto slotAddr = [](int s) {
      const int row = s >> 2, c = s & 3, rr = row & 15;
      return (row >> 4) * 512 + (rr * 4 + (c ^ ((rr >> 1) & 3))) * 8;
    };
    aWr0 = slotAddr(t);
    aWr1 = slotAddr(t + 512);
  }

  auto stage = [&](int buf, int k0) {
    bf16_t* lBb = lB + (buf << 14);   // buf * 512*32
    bf16_t* lAb = lA + (buf << 13);   // buf * 256*32
    // B tile: 32 windows, wave w does windows {8i+w : i<4}
#pragma unroll
    for (int i = 0; i < 4; ++i) {
      const int W = i * 8 + w;
      const bf16_t* gp = Bw + (size_t)(n0 + 16 * W + srow) * K + (k0 + sq * 8);
      GLOAD_LDS16(gp, &lBb[W * 512]);
    }
    if constexpr (EPI == 0) {
      // A fp32 -> bf16 via regs, swizzled ds_write_b128 (2 slots/thread)
#pragma unroll
      for (int hs = 0; hs < 2; ++hs) {
        const int s = t + 512 * hs;
        const float* src = Af32 + (size_t)(m0 + (s >> 2)) * lda + (k0 + (s & 3) * 8);
        float4 u0 = *(const float4*)src;
        float4 u1 = *(const float4*)(src + 4);
        bf16x8 v;
        v[0] = (bf16_t)u0.x; v[1] = (bf16_t)u0.y; v[2] = (bf16_t)u0.z; v[3] = (bf16_t)u0.w;
        v[4] = (bf16_t)u1.x; v[5] = (bf16_t)u1.y; v[6] = (bf16_t)u1.z; v[7] = (bf16_t)u1.w;
        *(bf16x8*)&lAb[hs ? aWr1 : aWr0] = v;
      }
    } else {
      // A tile: 16 windows, wave w does windows {8i+w : i<2}
#pragma unroll
      for (int i = 0; i < 2; ++i) {
        const int W = i * 8 + w;
        const bf16_t* gp = Abf + (size_t)(m0 + 16 * W + srow) * lda + (k0 + sq * 8);
        GLOAD_LDS16(gp, &lAb[W * 512]);
      }
    }
  };

  auto compute = [&](int buf) {
    const bf16_t* lAb = lA + (buf << 13);
    const bf16_t* lBb = lB + (buf << 14);
    bf16x8 af[8];
#pragma unroll
    for (int i = 0; i < 8; ++i) af[i] = *(const bf16x8*)&lAb[(8 * wr + i) * 512 + fRd];
#pragma unroll
    for (int j = 0; j < 8; ++j) {
      const bf16x8 bj = *(const bf16x8*)&lBb[(8 * wc + j) * 512 + fRd];
      __builtin_amdgcn_s_setprio(1);
#pragma unroll
      for (int i = 0; i < 8; ++i)
        acc[i][j] = __builtin_amdgcn_mfma_f32_16x16x32_bf16(af[i], bj, acc[i][j], 0, 0, 0);
      __builtin_amdgcn_s_setprio(0);
    }
  };

  if constexpr (EPI == 0) {
    // safe 2-phase loop (A path mixes global loads + ds_writes)
    stage(0, 0);
    __syncthreads();
    int cur = 0;
    for (int s = 1; s < S; ++s) {
      stage(cur ^ 1, s * 32);
      compute(cur);
      __syncthreads();
      cur ^= 1;
    }
    compute(cur);
    __syncthreads();  // protect rs/rss reuse below
  } else {
    // counted-vmcnt pipeline: exactly 6 DMAs per wave per step
    stage(0, 0);
    int cur = 0;
    for (int s = 0; s < S; ++s) {
      if (s + 1 < S) {
        stage(cur ^ 1, (s + 1) * 32);
        asm volatile("s_waitcnt vmcnt(6)" ::: "memory");  // current tile done; next in flight
      } else {
        asm volatile("s_waitcnt vmcnt(0)" ::: "memory");
      }
      __builtin_amdgcn_s_barrier();   // all waves: buf[cur] resident
      compute(cur);
      __builtin_amdgcn_s_barrier();   // all reads of buf[cur] done before overwrite
      cur ^= 1;
    }
  }

  if constexpr (EPI == 1) {
#pragma unroll
    for (int j = 0; j < 8; ++j) {
      const int colg = n0 + 128 * wc + 16 * j + r;
      const float bb = bias[colg];
#pragma unroll
      for (int i = 0; i < 8; ++i)
#pragma unroll
        for (int p = 0; p < 4; ++p) {
          const int rowg = m0 + 128 * wr + 16 * i + 4 * q + p;
          float v = acc[i][j][p] + bb;
          float g = 0.5f * v * (1.0f + erff(v * 0.70710678118654752f));
          outBf[(size_t)rowg * 1024 + colg] = (bf16_t)g;
        }
    }
  } else {
    float s_[8][4], ss[8][4];
#pragma unroll
    for (int i = 0; i < 8; ++i)
#pragma unroll
      for (int p = 0; p < 4; ++p) { s_[i][p] = 0.f; ss[i][p] = 0.f; }

#pragma unroll
    for (int j = 0; j < 8; ++j) {
      const int col = 128 * wc + 16 * j + r;
      const float bb = bias[col];
#pragma unroll
      for (int i = 0; i < 8; ++i)
#pragma unroll
        for (int p = 0; p < 4; ++p) {
          const int rowg = m0 + 128 * wr + 16 * i + 4 * q + p;
          float v = acc[i][j][p] + bb;
          if constexpr (EPI == 0) v += cellRes[(size_t)rowg * 512 + col];
          else                    v += (float)xRes[(size_t)rowg * 512 + col];
          acc[i][j][p] = v;
          s_[i][p] += v;
          ss[i][p] += v * v;
        }
    }
    // quad (16-lane) butterfly reduce over r
#pragma unroll
    for (int m = 1; m <= 8; m <<= 1) {
#pragma unroll
      for (int i = 0; i < 8; ++i)
#pragma unroll
        for (int p = 0; p < 4; ++p) {
          s_[i][p] += __shfl_xor(s_[i][p], m);
          ss[i][p] += __shfl_xor(ss[i][p], m);
        }
    }
    if (r == 0) {
#pragma unroll
      for (int i = 0; i < 8; ++i)
#pragma unroll
        for (int p = 0; p < 4; ++p) {
          const int rl = 128 * wr + 16 * i + 4 * q + p;
          rs[wc][rl] = s_[i][p];
          rss[wc][rl] = ss[i][p];
        }
    }
    __syncthreads();
    float mu[8][4], inv[8][4];
#pragma unroll
    for (int i = 0; i < 8; ++i)
#pragma unroll
      for (int p = 0; p < 4; ++p) {
        const int rl = 128 * wr + 16 * i + 4 * q + p;
        float tS = rs[0][rl] + rs[1][rl] + rs[2][rl] + rs[3][rl];
        float tQ = rss[0][rl] + rss[1][rl] + rss[2][rl] + rss[3][rl];
        float m_ = tS * (1.0f / 512.0f);
        float v_ = tQ * (1.0f / 512.0f) - m_ * m_;
        mu[i][p] = m_;
        inv[i][p] = rsqrtf(v_ + 1e-5f);
      }
#pragma unroll
    for (int j = 0; j < 8; ++j) {
      const int col = 128 * wc + 16 * j + r;
      const float ga = gamma[col], be = beta[col];
#pragma unroll
      for (int i = 0; i < 8; ++i)
#pragma unroll
        for (int p = 0; p < 4; ++p) {
          const int rowg = m0 + 128 * wr + 16 * i + 4 * q + p;
          float v = (acc[i][j][p] - mu[i][p]) * inv[i][p] * ga + be;
          if constexpr (EPI == 0) outBf[(size_t)rowg * 512 + col] = (bf16_t)v;
          else                    outF32[(size_t)rowg * 512 + col] = v;
        }
    }
  }
}

// distinct names for per-stage rocprof attribution
__global__ __launch_bounds__(512, 1) void gemm_g1(
    const float* Af32, const bf16_t* Bw, const float* bias, const float* cellRes,
    const float* gamma, const float* beta, bf16_t* outBf) {
  gemm_body<256, 0>(Af32, nullptr, 256, Bw, bias, cellRes, nullptr, gamma, beta, outBf, nullptr);
}
__global__ __launch_bounds__(512, 1) void gemm_g2(
    const bf16_t* Abf, const bf16_t* Bw, const float* bias, bf16_t* outBf) {
  gemm_body<512, 1>(nullptr, Abf, 512, Bw, bias, nullptr, nullptr, nullptr, nullptr, outBf, nullptr);
}
__global__ __launch_bounds__(512, 1) void gemm_g3(
    const bf16_t* Abf, const bf16_t* Bw, const float* bias, const bf16_t* xRes,
    const float* gamma, const float* beta, float* outF32) {
  gemm_body<1024, 2>(nullptr, Abf, 1024, Bw, bias, nullptr, xRes, gamma, beta, nullptr, outF32);
}

extern "C" void kernel_launch(void* const* d_in, const int* in_sizes, int n_in,
                              void* d_out, int out_size, void* d_ws, size_t ws_size,
                              hipStream_t stream) {
  const float* cell = (const float*)d_in[0];
  const float* pert = (const float*)d_in[1];
  const float* Wp   = (const float*)d_in[2];
  const float* bp   = (const float*)d_in[3];
  // d_in[4..7] = Wq,bq,Wk,bk: dead (softmax over a single key == 1 -> attn = v)
  const float* Wv   = (const float*)d_in[8];
  const float* bv   = (const float*)d_in[9];
  const float* Wo   = (const float*)d_in[10];
  const float* bo   = (const float*)d_in[11];
  const float* g1   = (const float*)d_in[12];
  const float* be1  = (const float*)d_in[13];
  const float* g2   = (const float*)d_in[14];
  const float* be2  = (const float*)d_in[15];
  const float* W1   = (const float*)d_in[16];
  const float* b1   = (const float*)d_in[17];
  const float* W2   = (const float*)d_in[18];
  const float* b2   = (const float*)d_in[19];

  char* ws = (char*)d_ws;
  float*  Wvp   = (float*)(ws + 0);          // 512*256*4   = 524288
  float*  bvp   = (float*)(ws + 524288);     // 512*4 (pad) = 2048
  float*  bcomb = (float*)(ws + 526336);     // 512*4 (pad) = 2048
  bf16_t* Wc    = (bf16_t*)(ws + 528384);    // 512*256*2   = 262144
  bf16_t* W1b   = (bf16_t*)(ws + 790528);    // 1024*512*2  = 1048576
  bf16_t* W2b   = (bf16_t*)(ws + 1839104);   // 512*1024*2  = 1048576
  bf16_t* xws   = (bf16_t*)(ws + 2887680);   // 65536*512*2 = 67108864
  bf16_t* hws   = (bf16_t*)(ws + 69996544);  // 65536*1024*2 = 134217728
  (void)in_sizes; (void)n_in; (void)out_size; (void)ws_size;

  prep_wvp<<<512, 256, 0, stream>>>(Wv, Wp, bp, bv, Wvp, bvp);
  prep_wc<<<512, 256, 0, stream>>>(Wo, bo, Wvp, bvp, Wc, bcomb);
  prep_cast<<<512, 256, 0, stream>>>(W1, W2, W1b, W2b);

  // G1: attn (pert @ Wc.T + bcomb) + cell residual + LN1 -> x bf16
  gemm_g1<<<dim3(256, 1), 512, 0, stream>>>(pert, Wc, bcomb, cell, g1, be1, xws);
  // G2: h = gelu(x @ W1.T + b1) -> bf16
  gemm_g2<<<dim3(256, 2), 512, 0, stream>>>(xws, W1b, b1, hws);
  // G3: out = LN2(x + h @ W2.T + b2) -> fp32
  gemm_g3<<<dim3(256, 1), 512, 0, stream>>>(hws, W2b, b2, xws, g2, be2, (float*)d_out);
}

// Round 7
// 769.931 us; speedup vs baseline: 2.1863x; 2.1863x over previous
//
#include <hip/hip_runtime.h>
#include <hip/hip_bf16.h>

typedef __bf16 bf16_t;
typedef __attribute__((ext_vector_type(8))) __bf16 bf16x8;
typedef __attribute__((ext_vector_type(4))) float f32x4;

// Direct HBM->LDS DMA, 16B per lane. LDS dest = wave-uniform base + lane*16.
#define GLOAD_LDS16(gp, lp)                                                    \
  __builtin_amdgcn_global_load_lds(                                            \
      (const __attribute__((address_space(1))) void*)(gp),                     \
      (__attribute__((address_space(3))) void*)(lp), 16, 0, 0)

// ---------------- prep kernels (tiny) ----------------
__global__ void prep_wvp(const float* __restrict__ Wv, const float* __restrict__ Wp,
                         const float* __restrict__ bp, const float* __restrict__ bv,
                         float* __restrict__ Wvp, float* __restrict__ bvp) {
  const int i = blockIdx.x;
  const int j = threadIdx.x;
  float a = 0.f;
  for (int d = 0; d < 512; ++d) a += Wv[i * 512 + d] * Wp[d * 256 + j];
  Wvp[i * 256 + j] = a;
  if (j == 0) {
    float b = 0.f;
    for (int d = 0; d < 512; ++d) b += Wv[i * 512 + d] * bp[d];
    bvp[i] = b + bv[i];
  }
}

// Packed-B layout (harness-verified in round 4), N x K row-major source:
//   B[n][k] -> Bp[(((n>>4)*(K/32) + (k>>5))*64 + ((k>>3)&3)*16 + (n&15))*8 + (k&7)]
// For each 16-col group g and K-step t: 64 lanes x 16B contiguous (1 KB) in exact
// per-wave MFMA B-fragment order. A wave's fragment load = ONE coalesced 1KB read.

__global__ void prep_wc(const float* __restrict__ Wo, const float* __restrict__ bo,
                        const float* __restrict__ Wvp, const float* __restrict__ bvp,
                        bf16_t* __restrict__ Wc, float* __restrict__ bcomb) {
  const int o = blockIdx.x;
  const int j = threadIdx.x;
  float a = 0.f;
  for (int i = 0; i < 512; ++i) a += Wo[o * 512 + i] * Wvp[i * 256 + j];
  const int g = o >> 4, rr = o & 15, t = j >> 5, q = (j >> 3) & 3, e = j & 7;
  Wc[((((size_t)g * 8 + t) * 64) + q * 16 + rr) * 8 + e] = (bf16_t)a;  // S=8
  if (j == 0) {
    float b = 0.f;
    for (int i = 0; i < 512; ++i) b += Wo[o * 512 + i] * bvp[i];
    bcomb[o] = b + bo[o];
  }
}

// cast W1 (N=1024,K=512) then W2 (N=512,K=1024) to bf16, packed layout
__global__ void prep_cast(const float* __restrict__ W1, const float* __restrict__ W2,
                          bf16_t* __restrict__ W1b, bf16_t* __restrict__ W2b) {
  const int idx = (blockIdx.x * 256 + threadIdx.x) * 8;
  const float* s;
  bf16_t* d;
  if (idx < 524288) {  // W1: K=512, S=16
    const int o = idx >> 9, k = idx & 511;
    const int g = o >> 4, rr = o & 15, t = k >> 5, q = (k >> 3) & 3;
    s = W1 + idx;
    d = W1b + ((((size_t)g * 16 + t) * 64) + q * 16 + rr) * 8;
  } else {             // W2: K=1024, S=32
    const int i2 = idx - 524288;
    const int o = i2 >> 10, k = i2 & 1023;
    const int g = o >> 4, rr = o & 15, t = k >> 5, q = (k >> 3) & 3;
    s = W2 + i2;
    d = W2b + ((((size_t)g * 32 + t) * 64) + q * 16 + rr) * 8;
  }
  float4 u0 = *(const float4*)s;
  float4 u1 = *(const float4*)(s + 4);
  bf16x8 v;
  v[0] = (bf16_t)u0.x; v[1] = (bf16_t)u0.y; v[2] = (bf16_t)u0.z; v[3] = (bf16_t)u0.w;
  v[4] = (bf16_t)u1.x; v[5] = (bf16_t)u1.y; v[6] = (bf16_t)u1.z; v[7] = (bf16_t)u1.w;
  *(bf16x8*)d = v;
}

// ---------------- fused GEMM body ----------------
// C[m][n] = sum_k A[m][k] * B[n][k]  (X @ W.T), B pre-packed in fragment order.
//
// ROUND-7 STRUCTURE (latency-bound diagnosis, rounds 0-6 all ~15% MfmaUtil):
//  - Tile 64 rows x 512 cols, 256 threads = 4 waves, wave-tile 64x128
//    (acc[4][8] = 128 regs -- proven no-spill footprint from round 5).
//  - A resident in LDS for the FULL K (64xK = 32/64/128 KB): loaded ONCE
//    (swizzled windows, verified conflict-free), one __syncthreads, then the
//    K-loop has ZERO barriers and ZERO LDS writes -> no per-step vmcnt drain,
//    no barrier serialization (m233: that was ~72% of the 2-phase critical path).
//  - B streamed L2->REG from the packed layout (1KB coalesced per fragment),
//    software ping-pong bA/bB half-a-step ahead; compiler inserts counted
//    vmcnt waits. B never touches LDS (zero cross-wave reuse anyway).
//
// EPI 0: + bias + cell residual, LayerNorm(g,b) -> bf16 out (stride 512)
// EPI 1: + bias, exact GELU -> bf16 out (stride 1024)
// EPI 2: + bias + bf16 x residual, LayerNorm -> fp32 out (stride 512)
// Epilogue stores are j-inner: consecutive instructions fill each row's 256B
// span -> L2 write-combining (attacks G2's measured 2.3x write amplification).
template <int K, int EPI>
__device__ __forceinline__ void gemm_body(
    const float* __restrict__ Af32, const bf16_t* __restrict__ Abf, const int lda,
    const bf16_t* __restrict__ Bp,
    const float* __restrict__ bias,
    const float* __restrict__ cellRes,
    const bf16_t* __restrict__ xRes,
    const float* __restrict__ gamma, const float* __restrict__ beta,
    bf16_t* __restrict__ outBf, float* __restrict__ outF32) {

  constexpr int S = K / 32;
  __shared__ __align__(16) bf16_t lA[64 * K];   // full-K A, windowed+swizzled
  __shared__ float rs[4][64];
  __shared__ float rss[4][64];

  const int t = threadIdx.x;
  const int m0 = blockIdx.x * 64;
  const int n0 = blockIdx.y * 512;  // only nonzero for EPI==1 (N=1024)
  const int lane = t & 63;
  const int w = t >> 6;             // wave 0..3 = col quarter
  const int r = lane & 15;
  const int q = lane >> 4;
  const int qs = q ^ ((r >> 1) & 3);
  const int fRd = r * 32 + qs * 8;  // within-window fragment read base

  // staging source mapping: lane l -> (row_in_window = l>>2, chunk = (l&3)^((l>>3)&3))
  const int srow = lane >> 2;
  const int sq = (lane & 3) ^ ((lane >> 3) & 3);

  // ---- A load: once, full K ----
  if constexpr (EPI == 0) {
    // fp32 -> bf16 convert; 2048 16B-slots (64 rows x 32 chunks), 8 per thread
#pragma unroll
    for (int u = 0; u < 8; ++u) {
      const int g = u * 256 + t;
      const int row = g >> 5;
      const int c = g & 31;
      const int rr = row & 15;
      const int addr = ((c >> 2) * 4 + (row >> 4)) * 512 +
                       (rr * 4 + ((c & 3) ^ ((rr >> 1) & 3))) * 8;
      const float* src = Af32 + (size_t)(m0 + row) * lda + c * 8;
      float4 u0 = *(const float4*)src;
      float4 u1 = *(const float4*)(src + 4);
      bf16x8 v;
      v[0] = (bf16_t)u0.x; v[1] = (bf16_t)u0.y; v[2] = (bf16_t)u0.z; v[3] = (bf16_t)u0.w;
      v[4] = (bf16_t)u1.x; v[5] = (bf16_t)u1.y; v[6] = (bf16_t)u1.z; v[7] = (bf16_t)u1.w;
      *(bf16x8*)&lA[addr] = v;
    }
  } else {
    // DMA: wave w stages row-group w of every K-step window
#pragma unroll
    for (int u = 0; u < S; ++u) {
      const bf16_t* gp = Abf + (size_t)(m0 + 16 * w + srow) * lda + (u * 32 + sq * 8);
      GLOAD_LDS16(gp, &lA[(u * 4 + w) * 512]);
    }
  }
  __syncthreads();  // drains vmcnt+lgkmcnt: A fully resident; ONLY barrier before epilogue

  // ---- B fragment stream (packed) ----
  const int g0 = (n0 >> 4) + 8 * w;
  auto bfrag = [&](int j, int s) {
    return *(const bf16x8*)(Bp + ((size_t)((g0 + j) * S + s) * 64 + lane) * 8);
  };

  f32x4 acc[4][8];
#pragma unroll
  for (int i = 0; i < 4; ++i)
#pragma unroll
    for (int j = 0; j < 8; ++j)
#pragma unroll
      for (int p = 0; p < 4; ++p) acc[i][j][p] = 0.f;

  bf16x8 bA[4], bB[4];
#pragma unroll
  for (int j = 0; j < 4; ++j) bA[j] = bfrag(j, 0);

#pragma unroll 2
  for (int s = 0; s < S; ++s) {
#pragma unroll
    for (int j = 0; j < 4; ++j) bB[j] = bfrag(4 + j, s);
    bf16x8 af[4];
#pragma unroll
    for (int i = 0; i < 4; ++i) af[i] = *(const bf16x8*)&lA[(s * 4 + i) * 512 + fRd];
    __builtin_amdgcn_s_setprio(1);
#pragma unroll
    for (int j = 0; j < 4; ++j)
#pragma unroll
      for (int i = 0; i < 4; ++i)
        acc[i][j] = __builtin_amdgcn_mfma_f32_16x16x32_bf16(af[i], bA[j], acc[i][j], 0, 0, 0);
    __builtin_amdgcn_s_setprio(0);
    if (s + 1 < S) {
#pragma unroll
      for (int j = 0; j < 4; ++j) bA[j] = bfrag(j, s + 1);  // next-step prefetch
    }
    __builtin_amdgcn_s_setprio(1);
#pragma unroll
    for (int j = 0; j < 4; ++j)
#pragma unroll
      for (int i = 0; i < 4; ++i)
        acc[i][4 + j] = __builtin_amdgcn_mfma_f32_16x16x32_bf16(af[i], bB[j], acc[i][4 + j], 0, 0, 0);
    __builtin_amdgcn_s_setprio(0);
  }

  if constexpr (EPI == 1) {
    float bb[8];
#pragma unroll
    for (int j = 0; j < 8; ++j) bb[j] = bias[n0 + 128 * w + 16 * j + r];
#pragma unroll
    for (int i = 0; i < 4; ++i)
#pragma unroll
      for (int p = 0; p < 4; ++p) {
        const int rowg = m0 + 16 * i + 4 * q + p;
        bf16_t* orow = outBf + (size_t)rowg * 1024 + (n0 + 128 * w + r);
#pragma unroll
        for (int j = 0; j < 8; ++j) {
          float v = acc[i][j][p] + bb[j];
          float g = 0.5f * v * (1.0f + erff(v * 0.70710678118654752f));
          orow[16 * j] = (bf16_t)g;
        }
      }
  } else {
    float s_[4][4], ss[4][4];
#pragma unroll
    for (int i = 0; i < 4; ++i)
#pragma unroll
      for (int p = 0; p < 4; ++p) { s_[i][p] = 0.f; ss[i][p] = 0.f; }
    float bb[8];
#pragma unroll
    for (int j = 0; j < 8; ++j) bb[j] = bias[128 * w + 16 * j + r];

#pragma unroll
    for (int i = 0; i < 4; ++i)
#pragma unroll
      for (int p = 0; p < 4; ++p) {
        const int rowg = m0 + 16 * i + 4 * q + p;
#pragma unroll
        for (int j = 0; j < 8; ++j) {
          const int col = 128 * w + 16 * j + r;
          float v = acc[i][j][p] + bb[j];
          if constexpr (EPI == 0) v += cellRes[(size_t)rowg * 512 + col];
          else                    v += (float)xRes[(size_t)rowg * 512 + col];
          acc[i][j][p] = v;
          s_[i][p] += v;
          ss[i][p] += v * v;
        }
      }
    // quad (16-lane) butterfly reduce over r
#pragma unroll
    for (int m = 1; m <= 8; m <<= 1) {
#pragma unroll
      for (int i = 0; i < 4; ++i)
#pragma unroll
        for (int p = 0; p < 4; ++p) {
          s_[i][p] += __shfl_xor(s_[i][p], m);
          ss[i][p] += __shfl_xor(ss[i][p], m);
        }
    }
    if (r == 0) {
#pragma unroll
      for (int i = 0; i < 4; ++i)
#pragma unroll
        for (int p = 0; p < 4; ++p) {
          rs[w][16 * i + 4 * q + p] = s_[i][p];
          rss[w][16 * i + 4 * q + p] = ss[i][p];
        }
    }
    __syncthreads();
    float mu[4][4], inv[4][4];
#pragma unroll
    for (int i = 0; i < 4; ++i)
#pragma unroll
      for (int p = 0; p < 4; ++p) {
        const int rl = 16 * i + 4 * q + p;
        float tS = rs[0][rl] + rs[1][rl] + rs[2][rl] + rs[3][rl];
        float tQ = rss[0][rl] + rss[1][rl] + rss[2][rl] + rss[3][rl];
        float m_ = tS * (1.0f / 512.0f);
        float v_ = tQ * (1.0f / 512.0f) - m_ * m_;
        mu[i][p] = m_;
        inv[i][p] = rsqrtf(v_ + 1e-5f);
      }
    float ga[8], be[8];
#pragma unroll
    for (int j = 0; j < 8; ++j) {
      ga[j] = gamma[128 * w + 16 * j + r];
      be[j] = beta[128 * w + 16 * j + r];
    }
#pragma unroll
    for (int i = 0; i < 4; ++i)
#pragma unroll
      for (int p = 0; p < 4; ++p) {
        const int rowg = m0 + 16 * i + 4 * q + p;
#pragma unroll
        for (int j = 0; j < 8; ++j) {
          const int col = 128 * w + 16 * j + r;
          float v = (acc[i][j][p] - mu[i][p]) * inv[i][p] * ga[j] + be[j];
          if constexpr (EPI == 0) outBf[(size_t)rowg * 512 + col] = (bf16_t)v;
          else                    outF32[(size_t)rowg * 512 + col] = v;
        }
      }
  }
}

// distinct names for per-stage rocprof attribution
__global__ __launch_bounds__(256, 2) void gemm_g1(
    const float* Af32, const bf16_t* Bw, const float* bias, const float* cellRes,
    const float* gamma, const float* beta, bf16_t* outBf) {
  gemm_body<256, 0>(Af32, nullptr, 256, Bw, bias, cellRes, nullptr, gamma, beta, outBf, nullptr);
}
__global__ __launch_bounds__(256, 2) void gemm_g2(
    const bf16_t* Abf, const bf16_t* Bw, const float* bias, bf16_t* outBf) {
  gemm_body<512, 1>(nullptr, Abf, 512, Bw, bias, nullptr, nullptr, nullptr, nullptr, outBf, nullptr);
}
__global__ __launch_bounds__(256, 1) void gemm_g3(   // LDS-capped to 1 block/CU anyway
    const bf16_t* Abf, const bf16_t* Bw, const float* bias, const bf16_t* xRes,
    const float* gamma, const float* beta, float* outF32) {
  gemm_body<1024, 2>(nullptr, Abf, 1024, Bw, bias, nullptr, xRes, gamma, beta, nullptr, outF32);
}

extern "C" void kernel_launch(void* const* d_in, const int* in_sizes, int n_in,
                              void* d_out, int out_size, void* d_ws, size_t ws_size,
                              hipStream_t stream) {
  const float* cell = (const float*)d_in[0];
  const float* pert = (const float*)d_in[1];
  const float* Wp   = (const float*)d_in[2];
  const float* bp   = (const float*)d_in[3];
  // d_in[4..7] = Wq,bq,Wk,bk: dead (softmax over a single key == 1 -> attn = v)
  const float* Wv   = (const float*)d_in[8];
  const float* bv   = (const float*)d_in[9];
  const float* Wo   = (const float*)d_in[10];
  const float* bo   = (const float*)d_in[11];
  const float* g1   = (const float*)d_in[12];
  const float* be1  = (const float*)d_in[13];
  const float* g2   = (const float*)d_in[14];
  const float* be2  = (const float*)d_in[15];
  const float* W1   = (const float*)d_in[16];
  const float* b1   = (const float*)d_in[17];
  const float* W2   = (const float*)d_in[18];
  const float* b2   = (const float*)d_in[19];

  char* ws = (char*)d_ws;
  float*  Wvp   = (float*)(ws + 0);          // 512*256*4   = 524288
  float*  bvp   = (float*)(ws + 524288);     // 512*4 (pad) = 2048
  float*  bcomb = (float*)(ws + 526336);     // 512*4 (pad) = 2048
  bf16_t* Wc    = (bf16_t*)(ws + 528384);    // 512*256*2   = 262144 (packed)
  bf16_t* W1b   = (bf16_t*)(ws + 790528);    // 1024*512*2  = 1048576 (packed)
  bf16_t* W2b   = (bf16_t*)(ws + 1839104);   // 512*1024*2  = 1048576 (packed)
  bf16_t* xws   = (bf16_t*)(ws + 2887680);   // 65536*512*2 = 67108864
  bf16_t* hws   = (bf16_t*)(ws + 69996544);  // 65536*1024*2 = 134217728
  (void)in_sizes; (void)n_in; (void)out_size; (void)ws_size;

  prep_wvp<<<512, 256, 0, stream>>>(Wv, Wp, bp, bv, Wvp, bvp);
  prep_wc<<<512, 256, 0, stream>>>(Wo, bo, Wvp, bvp, Wc, bcomb);
  prep_cast<<<512, 256, 0, stream>>>(W1, W2, W1b, W2b);

  // G1: attn (pert @ Wc.T + bcomb) + cell residual + LN1 -> x bf16
  gemm_g1<<<dim3(1024, 1), 256, 0, stream>>>(pert, Wc, bcomb, cell, g1, be1, xws);
  // G2: h = gelu(x @ W1.T + b1) -> bf16
  gemm_g2<<<dim3(1024, 2), 256, 0, stream>>>(xws, W1b, b1, hws);
  // G3: out = LN2(x + h @ W2.T + b2) -> fp32
  gemm_g3<<<dim3(1024, 1), 256, 0, stream>>>(hws, W2b, b2, xws, g2, be2, (float*)d_out);
}

// Round 8
// 638.144 us; speedup vs baseline: 2.6379x; 1.2065x over previous
//
#include <hip/hip_runtime.h>
#include <hip/hip_bf16.h>

typedef __bf16 bf16_t;
typedef __attribute__((ext_vector_type(8))) __bf16 bf16x8;
typedef __attribute__((ext_vector_type(4))) float f32x4;

// Direct HBM->LDS DMA, 16B per lane. LDS dest = wave-uniform base + lane*16.
#define GLOAD_LDS16(gp, lp)                                                    \
  __builtin_amdgcn_global_load_lds(                                            \
      (const __attribute__((address_space(1))) void*)(gp),                     \
      (__attribute__((address_space(3))) void*)(lp), 16, 0, 0)

// ---------------- prep kernels (tiny) ----------------
__global__ void prep_wvp(const float* __restrict__ Wv, const float* __restrict__ Wp,
                         const float* __restrict__ bp, const float* __restrict__ bv,
                         float* __restrict__ Wvp, float* __restrict__ bvp) {
  const int i = blockIdx.x;
  const int j = threadIdx.x;
  float a = 0.f;
  for (int d = 0; d < 512; ++d) a += Wv[i * 512 + d] * Wp[d * 256 + j];
  Wvp[i * 256 + j] = a;
  if (j == 0) {
    float b = 0.f;
    for (int d = 0; d < 512; ++d) b += Wv[i * 512 + d] * bp[d];
    bvp[i] = b + bv[i];
  }
}

// Packed-B layout (harness-verified rounds 4 & 7), N x K row-major source:
//   B[n][k] -> Bp[(((n>>4)*(K/32) + (k>>5))*64 + ((k>>3)&3)*16 + (n&15))*8 + (k&7)]
// For each 16-col group g and K-step t: 64 lanes x 16B contiguous (1 KB) in exact
// per-wave MFMA B-fragment order. A wave's fragment load = ONE coalesced 1KB read.

__global__ void prep_wc(const float* __restrict__ Wo, const float* __restrict__ bo,
                        const float* __restrict__ Wvp, const float* __restrict__ bvp,
                        bf16_t* __restrict__ Wc, float* __restrict__ bcomb) {
  const int o = blockIdx.x;
  const int j = threadIdx.x;
  float a = 0.f;
  for (int i = 0; i < 512; ++i) a += Wo[o * 512 + i] * Wvp[i * 256 + j];
  const int g = o >> 4, rr = o & 15, t = j >> 5, q = (j >> 3) & 3, e = j & 7;
  Wc[((((size_t)g * 8 + t) * 64) + q * 16 + rr) * 8 + e] = (bf16_t)a;  // S=8
  if (j == 0) {
    float b = 0.f;
    for (int i = 0; i < 512; ++i) b += Wo[o * 512 + i] * bvp[i];
    bcomb[o] = b + bo[o];
  }
}

// cast W1 (N=1024,K=512) then W2 (N=512,K=1024) to bf16, packed layout
__global__ void prep_cast(const float* __restrict__ W1, const float* __restrict__ W2,
                          bf16_t* __restrict__ W1b, bf16_t* __restrict__ W2b) {
  const int idx = (blockIdx.x * 256 + threadIdx.x) * 8;
  const float* s;
  bf16_t* d;
  if (idx < 524288) {  // W1: K=512, S=16
    const int o = idx >> 9, k = idx & 511;
    const int g = o >> 4, rr = o & 15, t = k >> 5, q = (k >> 3) & 3;
    s = W1 + idx;
    d = W1b + ((((size_t)g * 16 + t) * 64) + q * 16 + rr) * 8;
  } else {             // W2: K=1024, S=32
    const int i2 = idx - 524288;
    const int o = i2 >> 10, k = i2 & 1023;
    const int g = o >> 4, rr = o & 15, t = k >> 5, q = (k >> 3) & 3;
    s = W2 + i2;
    d = W2b + ((((size_t)g * 32 + t) * 64) + q * 16 + rr) * 8;
  }
  float4 u0 = *(const float4*)s;
  float4 u1 = *(const float4*)(s + 4);
  bf16x8 v;
  v[0] = (bf16_t)u0.x; v[1] = (bf16_t)u0.y; v[2] = (bf16_t)u0.z; v[3] = (bf16_t)u0.w;
  v[4] = (bf16_t)u1.x; v[5] = (bf16_t)u1.y; v[6] = (bf16_t)u1.z; v[7] = (bf16_t)u1.w;
  *(bf16x8*)d = v;
}

// ---------------- fused GEMM body ----------------
// C[m][n] = sum_k A[m][k] * B[n][k]  (X @ W.T), B pre-packed in fragment order.
//
// ROUND-8: round-7 kept traffic ideal (FETCH/WRITE ~1.0x) but full-K LDS ->
// 1 block/CU -> serialized stage/compute/write phases (G3 194us, all counters
// low). Fix: tiny A double-buffer (BK=32, 2x4KB; LDS total ~10KB) -> 2
// blocks/CU restores cross-block phase overlap, while B stays as the
// reg-streamed packed fragments (zero LDS, 4-deep prefetch).
//
// K-loop (EPI!=0), ONE raw s_barrier per step, no drains:
//   stage(nb, s+1)        [1 DMA; sched_barrier pins it oldest]
//   bB loads (4)          [step s, second col-half]
//   af ds_reads; 16 MFMA (bA)
//   bA' loads (4)         [step s+1 prefetch]
//   16 MFMA (bB)
//   s_waitcnt vmcnt(4)    [in-order retire => own DMA done; bA' stays in flight]
//   s_barrier             [all waves: nb resident AND reads of cb done]
// Correctness: a wave's next DMA (into cb) is issued only after this barrier,
// and every wave finished reading cb before it -> no race, single barrier.
//
// EPI 0 (K=256): unchanged round-7 path -- full-K A in LDS (32 KB), loaded
// once (fp32->bf16 reg convert), one __syncthreads, barrier-free K-loop.
//
// EPI 0: + bias + cell residual, LayerNorm(g,b) -> bf16 out (stride 512)
// EPI 1: + bias, exact GELU -> bf16 out (stride 1024)
// EPI 2: + bias + bf16 x residual, LayerNorm -> fp32 out (stride 512)
template <int K, int EPI>
__device__ __forceinline__ void gemm_body(
    const float* __restrict__ Af32, const bf16_t* __restrict__ Abf, const int lda,
    const bf16_t* __restrict__ Bp,
    const float* __restrict__ bias,
    const float* __restrict__ cellRes,
    const bf16_t* __restrict__ xRes,
    const float* __restrict__ gamma, const float* __restrict__ beta,
    bf16_t* __restrict__ outBf, float* __restrict__ outF32) {

  constexpr int S = K / 32;
  constexpr int LAE = (EPI == 0) ? 64 * K : 2 * 64 * 32;  // bf16 elems
  __shared__ __align__(16) bf16_t lA[LAE];
  __shared__ float rs[4][64];
  __shared__ float rss[4][64];

  const int t = threadIdx.x;
  const int m0 = blockIdx.x * 64;
  const int n0 = blockIdx.y * 512;  // only nonzero for EPI==1 (N=1024)
  const int lane = t & 63;
  const int w = t >> 6;             // wave 0..3 = col quarter
  const int r = lane & 15;
  const int q = lane >> 4;
  const int qs = q ^ ((r >> 1) & 3);
  const int fRd = r * 32 + qs * 8;  // within-window fragment read base

  // staging source mapping: lane l -> (row_in_window = l>>2, chunk = (l&3)^((l>>3)&3))
  const int srow = lane >> 2;
  const int sq = (lane & 3) ^ ((lane >> 3) & 3);

  // ---- B fragment stream (packed) ----
  const int g0 = (n0 >> 4) + 8 * w;
  auto bfrag = [&](int j, int s) {
    return *(const bf16x8*)(Bp + ((size_t)((g0 + j) * S + s) * 64 + lane) * 8);
  };

  f32x4 acc[4][8];
#pragma unroll
  for (int i = 0; i < 4; ++i)
#pragma unroll
    for (int j = 0; j < 8; ++j)
#pragma unroll
      for (int p = 0; p < 4; ++p) acc[i][j][p] = 0.f;

  bf16x8 bA[4], bB[4];

  if constexpr (EPI == 0) {
    // ---- full-K A load once (fp32 -> bf16), round-7 verified ----
#pragma unroll
    for (int u = 0; u < (64 * K / 8) / 256; ++u) {
      const int g = u * 256 + t;
      const int row = g >> (K == 256 ? 5 : 6);
      const int c = g & ((K / 8) - 1);
      const int rr = row & 15;
      const int addr = ((c >> 2) * 4 + (row >> 4)) * 512 +
                       (rr * 4 + ((c & 3) ^ ((rr >> 1) & 3))) * 8;
      const float* src = Af32 + (size_t)(m0 + row) * lda + c * 8;
      float4 u0 = *(const float4*)src;
      float4 u1 = *(const float4*)(src + 4);
      bf16x8 v;
      v[0] = (bf16_t)u0.x; v[1] = (bf16_t)u0.y; v[2] = (bf16_t)u0.z; v[3] = (bf16_t)u0.w;
      v[4] = (bf16_t)u1.x; v[5] = (bf16_t)u1.y; v[6] = (bf16_t)u1.z; v[7] = (bf16_t)u1.w;
      *(bf16x8*)&lA[addr] = v;
    }
    __syncthreads();  // only barrier before epilogue

#pragma unroll
    for (int j = 0; j < 4; ++j) bA[j] = bfrag(j, 0);
#pragma unroll 2
    for (int s = 0; s < S; ++s) {
#pragma unroll
      for (int j = 0; j < 4; ++j) bB[j] = bfrag(4 + j, s);
      bf16x8 af[4];
#pragma unroll
      for (int i = 0; i < 4; ++i) af[i] = *(const bf16x8*)&lA[(s * 4 + i) * 512 + fRd];
      __builtin_amdgcn_s_setprio(1);
#pragma unroll
      for (int j = 0; j < 4; ++j)
#pragma unroll
        for (int i = 0; i < 4; ++i)
          acc[i][j] = __builtin_amdgcn_mfma_f32_16x16x32_bf16(af[i], bA[j], acc[i][j], 0, 0, 0);
      __builtin_amdgcn_s_setprio(0);
      if (s + 1 < S) {
#pragma unroll
        for (int j = 0; j < 4; ++j) bA[j] = bfrag(j, s + 1);
      }
      __builtin_amdgcn_s_setprio(1);
#pragma unroll
      for (int j = 0; j < 4; ++j)
#pragma unroll
        for (int i = 0; i < 4; ++i)
          acc[i][4 + j] = __builtin_amdgcn_mfma_f32_16x16x32_bf16(af[i], bB[j], acc[i][4 + j], 0, 0, 0);
      __builtin_amdgcn_s_setprio(0);
    }
  } else {
    // ---- dbuf A (2 x 64x32 = 2 x 4KB), 1 DMA/wave/step, 1 barrier/step ----
    auto stageA = [&](int buf, int s) {
      const bf16_t* gp = Abf + (size_t)(m0 + 16 * w + srow) * lda + (s * 32 + sq * 8);
      GLOAD_LDS16(gp, &lA[(buf << 11) + w * 512]);
    };
    // prologue: DMA tile0 (oldest), then bA(0); vmcnt(4) retires DMA only.
    stageA(0, 0);
    __builtin_amdgcn_sched_barrier(0);
#pragma unroll
    for (int j = 0; j < 4; ++j) bA[j] = bfrag(j, 0);
    asm volatile("s_waitcnt vmcnt(4)" ::: "memory");
    __builtin_amdgcn_s_barrier();

#pragma unroll 2
    for (int s = 0; s < S; ++s) {
      const int cb = s & 1;
      if (s + 1 < S) {
        stageA(cb ^ 1, s + 1);               // oldest vmem op of this step
        __builtin_amdgcn_sched_barrier(0);   // pin: nothing moves above/below
      }
#pragma unroll
      for (int j = 0; j < 4; ++j) bB[j] = bfrag(4 + j, s);
      bf16x8 af[4];
#pragma unroll
      for (int i = 0; i < 4; ++i) af[i] = *(const bf16x8*)&lA[(cb << 11) + i * 512 + fRd];
      __builtin_amdgcn_s_setprio(1);
#pragma unroll
      for (int j = 0; j < 4; ++j)
#pragma unroll
        for (int i = 0; i < 4; ++i)
          acc[i][j] = __builtin_amdgcn_mfma_f32_16x16x32_bf16(af[i], bA[j], acc[i][j], 0, 0, 0);
      __builtin_amdgcn_s_setprio(0);
      if (s + 1 < S) {
#pragma unroll
        for (int j = 0; j < 4; ++j) bA[j] = bfrag(j, s + 1);  // 4-deep prefetch
      }
      __builtin_amdgcn_s_setprio(1);
#pragma unroll
      for (int j = 0; j < 4; ++j)
#pragma unroll
        for (int i = 0; i < 4; ++i)
          acc[i][4 + j] = __builtin_amdgcn_mfma_f32_16x16x32_bf16(af[i], bB[j], acc[i][4 + j], 0, 0, 0);
      __builtin_amdgcn_s_setprio(0);
      if (s + 1 < S) {
        // own DMA retired (in-order; <=4 outstanding = the bA' prefetch)
        asm volatile("s_waitcnt vmcnt(4)" ::: "memory");
        __builtin_amdgcn_s_barrier();  // nb resident everywhere; cb reads done
      }
    }
  }

  if constexpr (EPI == 1) {
    float bb[8];
#pragma unroll
    for (int j = 0; j < 8; ++j) bb[j] = bias[n0 + 128 * w + 16 * j + r];
#pragma unroll
    for (int i = 0; i < 4; ++i)
#pragma unroll
      for (int p = 0; p < 4; ++p) {
        const int rowg = m0 + 16 * i + 4 * q + p;
        bf16_t* orow = outBf + (size_t)rowg * 1024 + (n0 + 128 * w + r);
#pragma unroll
        for (int j = 0; j < 8; ++j) {
          float v = acc[i][j][p] + bb[j];
          float g = 0.5f * v * (1.0f + erff(v * 0.70710678118654752f));
          orow[16 * j] = (bf16_t)g;
        }
      }
  } else {
    float s_[4][4], ss[4][4];
#pragma unroll
    for (int i = 0; i < 4; ++i)
#pragma unroll
      for (int p = 0; p < 4; ++p) { s_[i][p] = 0.f; ss[i][p] = 0.f; }
    float bb[8];
#pragma unroll
    for (int j = 0; j < 8; ++j) bb[j] = bias[128 * w + 16 * j + r];

#pragma unroll
    for (int i = 0; i < 4; ++i)
#pragma unroll
      for (int p = 0; p < 4; ++p) {
        const int rowg = m0 + 16 * i + 4 * q + p;
#pragma unroll
        for (int j = 0; j < 8; ++j) {
          const int col = 128 * w + 16 * j + r;
          float v = acc[i][j][p] + bb[j];
          if constexpr (EPI == 0) v += cellRes[(size_t)rowg * 512 + col];
          else                    v += (float)xRes[(size_t)rowg * 512 + col];
          acc[i][j][p] = v;
          s_[i][p] += v;
          ss[i][p] += v * v;
        }
      }
    // quad (16-lane) butterfly reduce over r
#pragma unroll
    for (int m = 1; m <= 8; m <<= 1) {
#pragma unroll
      for (int i = 0; i < 4; ++i)
#pragma unroll
        for (int p = 0; p < 4; ++p) {
          s_[i][p] += __shfl_xor(s_[i][p], m);
          ss[i][p] += __shfl_xor(ss[i][p], m);
        }
    }
    if (r == 0) {
#pragma unroll
      for (int i = 0; i < 4; ++i)
#pragma unroll
        for (int p = 0; p < 4; ++p) {
          rs[w][16 * i + 4 * q + p] = s_[i][p];
          rss[w][16 * i + 4 * q + p] = ss[i][p];
        }
    }
    __syncthreads();
    float mu[4][4], inv[4][4];
#pragma unroll
    for (int i = 0; i < 4; ++i)
#pragma unroll
      for (int p = 0; p < 4; ++p) {
        const int rl = 16 * i + 4 * q + p;
        float tS = rs[0][rl] + rs[1][rl] + rs[2][rl] + rs[3][rl];
        float tQ = rss[0][rl] + rss[1][rl] + rss[2][rl] + rss[3][rl];
        float m_ = tS * (1.0f / 512.0f);
        float v_ = tQ * (1.0f / 512.0f) - m_ * m_;
        mu[i][p] = m_;
        inv[i][p] = rsqrtf(v_ + 1e-5f);
      }
    float ga[8], be[8];
#pragma unroll
    for (int j = 0; j < 8; ++j) {
      ga[j] = gamma[128 * w + 16 * j + r];
      be[j] = beta[128 * w + 16 * j + r];
    }
#pragma unroll
    for (int i = 0; i < 4; ++i)
#pragma unroll
      for (int p = 0; p < 4; ++p) {
        const int rowg = m0 + 16 * i + 4 * q + p;
#pragma unroll
        for (int j = 0; j < 8; ++j) {
          const int col = 128 * w + 16 * j + r;
          float v = (acc[i][j][p] - mu[i][p]) * inv[i][p] * ga[j] + be[j];
          if constexpr (EPI == 0) outBf[(size_t)rowg * 512 + col] = (bf16_t)v;
          else                    outF32[(size_t)rowg * 512 + col] = v;
        }
      }
  }
}

// distinct names for per-stage rocprof attribution
__global__ __launch_bounds__(256, 2) void gemm_g1(
    const float* Af32, const bf16_t* Bw, const float* bias, const float* cellRes,
    const float* gamma, const float* beta, bf16_t* outBf) {
  gemm_body<256, 0>(Af32, nullptr, 256, Bw, bias, cellRes, nullptr, gamma, beta, outBf, nullptr);
}
__global__ __launch_bounds__(256, 2) void gemm_g2(
    const bf16_t* Abf, const bf16_t* Bw, const float* bias, bf16_t* outBf) {
  gemm_body<512, 1>(nullptr, Abf, 512, Bw, bias, nullptr, nullptr, nullptr, nullptr, outBf, nullptr);
}
__global__ __launch_bounds__(256, 2) void gemm_g3(
    const bf16_t* Abf, const bf16_t* Bw, const float* bias, const bf16_t* xRes,
    const float* gamma, const float* beta, float* outF32) {
  gemm_body<1024, 2>(nullptr, Abf, 1024, Bw, bias, nullptr, xRes, gamma, beta, nullptr, outF32);
}

extern "C" void kernel_launch(void* const* d_in, const int* in_sizes, int n_in,
                              void* d_out, int out_size, void* d_ws, size_t ws_size,
                              hipStream_t stream) {
  const float* cell = (const float*)d_in[0];
  const float* pert = (const float*)d_in[1];
  const float* Wp   = (const float*)d_in[2];
  const float* bp   = (const float*)d_in[3];
  // d_in[4..7] = Wq,bq,Wk,bk: dead (softmax over a single key == 1 -> attn = v)
  const float* Wv   = (const float*)d_in[8];
  const float* bv   = (const float*)d_in[9];
  const float* Wo   = (const float*)d_in[10];
  const float* bo   = (const float*)d_in[11];
  const float* g1   = (const float*)d_in[12];
  const float* be1  = (const float*)d_in[13];
  const float* g2   = (const float*)d_in[14];
  const float* be2  = (const float*)d_in[15];
  const float* W1   = (const float*)d_in[16];
  const float* b1   = (const float*)d_in[17];
  const float* W2   = (const float*)d_in[18];
  const float* b2   = (const float*)d_in[19];

  char* ws = (char*)d_ws;
  float*  Wvp   = (float*)(ws + 0);          // 512*256*4   = 524288
  float*  bvp   = (float*)(ws + 524288);     // 512*4 (pad) = 2048
  float*  bcomb = (float*)(ws + 526336);     // 512*4 (pad) = 2048
  bf16_t* Wc    = (bf16_t*)(ws + 528384);    // 512*256*2   = 262144 (packed)
  bf16_t* W1b   = (bf16_t*)(ws + 790528);    // 1024*512*2  = 1048576 (packed)
  bf16_t* W2b   = (bf16_t*)(ws + 1839104);   // 512*1024*2  = 1048576 (packed)
  bf16_t* xws   = (bf16_t*)(ws + 2887680);   // 65536*512*2 = 67108864
  bf16_t* hws   = (bf16_t*)(ws + 69996544);  // 65536*1024*2 = 134217728
  (void)in_sizes; (void)n_in; (void)out_size; (void)ws_size;

  prep_wvp<<<512, 256, 0, stream>>>(Wv, Wp, bp, bv, Wvp, bvp);
  prep_wc<<<512, 256, 0, stream>>>(Wo, bo, Wvp, bvp, Wc, bcomb);
  prep_cast<<<512, 256, 0, stream>>>(W1, W2, W1b, W2b);

  // G1: attn (pert @ Wc.T + bcomb) + cell residual + LN1 -> x bf16
  gemm_g1<<<dim3(1024, 1), 256, 0, stream>>>(pert, Wc, bcomb, cell, g1, be1, xws);
  // G2: h = gelu(x @ W1.T + b1) -> bf16
  gemm_g2<<<dim3(1024, 2), 256, 0, stream>>>(xws, W1b, b1, hws);
  // G3: out = LN2(x + h @ W2.T + b2) -> fp32
  gemm_g3<<<dim3(1024, 1), 256, 0, stream>>>(hws, W2b, b2, xws, g2, be2, (float*)d_out);
}